// Round 1
// baseline (560.675 us; speedup 1.0000x reference)
//
#include <hip/hip_runtime.h>

// ESN recurrence, MI355X.
// B=128 chains; each chain: 1023 sequential steps of
//   s[r] <- tanh(0.15*s[r+1] + 0.85*s[r-1] + dot(x[b,t,:], W[r,:]))  (circular)
// One block per chain, thread r <-> state element r.
// Sync: raw `s_waitcnt lgkmcnt(0); s_barrier` (NOT __syncthreads, which drains
// vmcnt(0) and would stall each step on the output store's HBM ack).
// LDS: ping-pong padded buffers sbuf[2][R+2] -> every thread reads a stride-1
// pair via one ds_read2; wrap elements duplicated by boundary threads.

#define B_DIM 128
#define T_DIM 1024
#define D_DIM 8
#define R_DIM 512

#define BETA_PLUS  0.15f   // coeff on s[r+1]
#define BETA_MINUS 0.85f   // coeff on s[r-1]

__device__ __forceinline__ float tanh_fast(float x) {
    // tanh(x) = 1 - 2/(exp(2x)+1); exp(2x) = exp2(x * 2*log2(e)).
    // Saturates correctly for |x| large (exp2->inf -> rcp->0 -> 1; exp2->0 -> -1).
#if __has_builtin(__builtin_amdgcn_exp2f) && __has_builtin(__builtin_amdgcn_rcpf)
    float e = __builtin_amdgcn_exp2f(x * 2.885390081777927f);
    return fmaf(-2.0f, __builtin_amdgcn_rcpf(e + 1.0f), 1.0f);
#else
    float e = exp2f(x * 2.885390081777927f);
    return 1.0f - 2.0f / (e + 1.0f);
#endif
}

__global__ __launch_bounds__(R_DIM) void esn_kernel(const float* __restrict__ x,
                                                    const float* __restrict__ W,
                                                    float* __restrict__ out) {
    const int b = blockIdx.x;
    const int r = threadIdx.x;

    __shared__ float sbuf[2][R_DIM + 2];

    // W row (8 floats) into registers, held for the whole chain.
    const float4 wa = *(const float4*)(W + r * D_DIM);
    const float4 wb = *(const float4*)(W + r * D_DIM + 4);

    const float* xb   = x + (size_t)b * T_DIM * D_DIM;
    float*       outb = out + (size_t)b * T_DIM * R_DIM + r;

    // Prefetch x[b,1,:] (wave-uniform address -> scalar loads).
    float4 xa = *(const float4*)(xb + 1 * D_DIM);
    float4 xc = *(const float4*)(xb + 1 * D_DIM + 4);

    float left = 0.0f, right = 0.0f;  // s_0 = 0

    for (int t = 1; t < T_DIM; ++t) {
        // u = dot(x[b,t,:], W[r,:]) -- 8 FMAs, overlaps the LDS read latency
        // of left/right issued at the end of the previous iteration.
        float u = xa.x * wa.x;
        u = fmaf(xa.y, wa.y, u);
        u = fmaf(xa.z, wa.z, u);
        u = fmaf(xa.w, wa.w, u);
        u = fmaf(xc.x, wb.x, u);
        u = fmaf(xc.y, wb.y, u);
        u = fmaf(xc.z, wb.z, u);
        u = fmaf(xc.w, wb.w, u);

        // Prefetch next timestep's x (clamped at the end; x[b,T-1] re-read).
        const int tn = (t + 1 < T_DIM) ? (t + 1) : t;
        xa = *(const float4*)(xb + tn * D_DIM);
        xc = *(const float4*)(xb + tn * D_DIM + 4);

        const float pre = fmaf(BETA_MINUS, left, fmaf(BETA_PLUS, right, u));
        const float s = tanh_fast(pre);

        // Fire-and-forget output store (coalesced across the 64-lane wave).
        outb[(t - 1) * R_DIM] = s;

        // Publish state. Padded layout: sbuf[p][i+1] = s_i, sbuf[p][0] = s_{R-1},
        // sbuf[p][R+1] = s_0  => every thread reads sbuf[p][r] (left) and
        // sbuf[p][r+2] (right): one ds_read2_b32, stride-1 (2-way alias, free).
        const int p = t & 1;
        sbuf[p][r + 1] = s;
        if (r == 0)         sbuf[p][R_DIM + 1] = s;
        if (r == R_DIM - 1) sbuf[p][0] = s;

        // LDS-only drain + barrier. Ping-pong buffers make one barrier per
        // step sufficient (writes to p at t+2 can only happen after barrier
        // t+1, by which time all reads of p from step t are consumed).
        asm volatile("s_waitcnt lgkmcnt(0)\n\ts_barrier" ::: "memory");

        left  = sbuf[p][r];
        right = sbuf[p][r + 2];
    }

    // Reference output's final timestep is all zeros (d_out is poisoned 0xAA).
    outb[(T_DIM - 1) * R_DIM] = 0.0f;
}

extern "C" void kernel_launch(void* const* d_in, const int* in_sizes, int n_in,
                              void* d_out, int out_size, void* d_ws, size_t ws_size,
                              hipStream_t stream) {
    const float* x = (const float*)d_in[0];   // [B, T, D] fp32
    const float* W = (const float*)d_in[1];   // [R, D] fp32
    float* out = (float*)d_out;               // [B, T, R] fp32

    esn_kernel<<<dim3(B_DIM), dim3(R_DIM), 0, stream>>>(x, W, out);
}

// Round 2
// 490.574 us; speedup vs baseline: 1.1429x; 1.1429x over previous
//
#include <hip/hip_runtime.h>

// ESN recurrence, MI355X — producer/consumer decomposition.
// One block per chain (b). Wave 0 ("consumer") holds all 512 state elements in
// registers (8 per lane, contiguous: lane l owns r = 8l..8l+7) and runs the
// serial recurrence with NO per-step barrier: neighbor exchange is two __shfl
// lane-rotations (only edge elements cross lanes). Waves 1-7 ("producers")
// compute u'(t,r) = 2log2(e) * dot(x[b,t,:], W[r,:]) into a double-buffered
// LDS ring, 16 timesteps per phase, one lgkm-only barrier per phase.
//
// The 2log2(e) tanh scale is folded into W (staged) and the beta constants,
// so the consumer's tanh is: s = 1 - 2*rcp(exp2(pre') + 1).
//
// Barriers are raw `s_waitcnt lgkmcnt(0); s_barrier` — __syncthreads would
// drain vmcnt(0) and stall on the consumer's fire-and-forget output stores.

#define B_DIM 128
#define T_DIM 1024
#define D_DIM 8
#define R_DIM 512
#define NT    16            // timesteps per phase
#define NPHASE 64           // covers 1023 steps (last phase has 15)

#define SC   2.8853900817779268f   // 2*log2(e)
#define BP_S (0.15f * SC)          // coeff on s[r+1], scaled
#define BM_S (0.85f * SC)          // coeff on s[r-1], scaled

__device__ __forceinline__ float esn_step(float L, float R, float u) {
    // pre' = 2log2e * (0.85 L + 0.15 R + u_raw); u already scaled.
    const float pre = fmaf(BM_S, L, fmaf(BP_S, R, u));
#if __has_builtin(__builtin_amdgcn_exp2f) && __has_builtin(__builtin_amdgcn_rcpf)
    const float e = __builtin_amdgcn_exp2f(pre);
    return fmaf(-2.0f, __builtin_amdgcn_rcpf(e + 1.0f), 1.0f);
#else
    const float e = exp2f(pre);
    return 1.0f - 2.0f / (e + 1.0f);
#endif
}

__device__ __forceinline__ void barrier_lds_only() {
    // LDS drain + barrier, WITHOUT vmcnt(0): pending global stores (consumer)
    // stay in flight across the barrier.
    asm volatile("s_waitcnt lgkmcnt(0)\n\ts_barrier" ::: "memory");
}

__global__ __launch_bounds__(512, 1) void esn_kernel(const float* __restrict__ x,
                                                     const float* __restrict__ W,
                                                     float* __restrict__ out) {
    __shared__ float Wl[R_DIM][D_DIM];       // scaled W, 16 KB
    __shared__ float ubuf[2][NT][R_DIM];     // u ring, 64 KB

    const int b   = blockIdx.x;
    const int tid = threadIdx.x;
    const float* xb = x + (size_t)b * T_DIM * D_DIM;

    // ---- Stage W * 2log2e into LDS; keep own row in regs for the prologue.
    const float4 wa = *(const float4*)(W + tid * D_DIM);
    const float4 wb = *(const float4*)(W + tid * D_DIM + 4);
    const float w0 = wa.x * SC, w1 = wa.y * SC, w2 = wa.z * SC, w3 = wa.w * SC;
    const float w4 = wb.x * SC, w5 = wb.y * SC, w6 = wb.z * SC, w7 = wb.w * SC;
    Wl[tid][0] = w0; Wl[tid][1] = w1; Wl[tid][2] = w2; Wl[tid][3] = w3;
    Wl[tid][4] = w4; Wl[tid][5] = w5; Wl[tid][6] = w6; Wl[tid][7] = w7;

    // ---- Prologue: all 512 threads fill phase 0 (t = 1..16), r = tid.
#pragma unroll
    for (int j = 0; j < NT; ++j) {
        const float4 xa = *(const float4*)(xb + (j + 1) * D_DIM);
        const float4 xc = *(const float4*)(xb + (j + 1) * D_DIM + 4);
        float u = xa.x * w0;
        u = fmaf(xa.y, w1, u); u = fmaf(xa.z, w2, u); u = fmaf(xa.w, w3, u);
        u = fmaf(xc.x, w4, u); u = fmaf(xc.y, w5, u);
        u = fmaf(xc.z, w6, u); u = fmaf(xc.w, w7, u);
        ubuf[0][j][tid] = u;
    }
    __syncthreads();  // one full barrier before the loop (no stores pending yet)

    const int wid  = tid >> 6;
    const int lane = tid & 63;

    if (wid == 0) {
        // ================= consumer =================
        asm volatile("s_setprio 3" ::: "memory");
        const int lp = (lane + 63) & 63;   // source of my left edge (s[7] of prev lane)
        const int ln = (lane + 1) & 63;    // source of my right edge (s[0] of next lane)
        float s[8];
#pragma unroll
        for (int e = 0; e < 8; ++e) s[e] = 0.0f;

        float* op = out + (size_t)b * T_DIM * R_DIM + lane * 8;

        for (int k = 0; k < NPHASE; ++k) {
            const float* ub = &ubuf[k & 1][0][lane * 8];
            const int steps = (k == NPHASE - 1) ? (1023 - NT * (NPHASE - 1)) : NT;
            float4 ua = *(const float4*)(ub);
            float4 uc = *(const float4*)(ub + 4);
            for (int tl = 0; tl < steps; ++tl) {
                // prefetch next step's u (off the critical path)
                const int tn = (tl + 1 < steps) ? (tl + 1) : tl;
                const float4 na = *(const float4*)(ub + tn * R_DIM);
                const float4 nc = *(const float4*)(ub + tn * R_DIM + 4);

                const float L0 = __shfl(s[7], lp, 64);  // r-1 of my element 0
                const float R7 = __shfl(s[0], ln, 64);  // r+1 of my element 7

                const float n0 = esn_step(L0,   s[1], ua.x);
                const float n1 = esn_step(s[0], s[2], ua.y);
                const float n2 = esn_step(s[1], s[3], ua.z);
                const float n3 = esn_step(s[2], s[4], ua.w);
                const float n4 = esn_step(s[3], s[5], uc.x);
                const float n5 = esn_step(s[4], s[6], uc.y);
                const float n6 = esn_step(s[5], s[7], uc.z);
                const float n7 = esn_step(s[6], R7,   uc.w);
                s[0] = n0; s[1] = n1; s[2] = n2; s[3] = n3;
                s[4] = n4; s[5] = n5; s[6] = n6; s[7] = n7;

                // fire-and-forget, coalesced 2 KB/wave
                *(float4*)(op)     = make_float4(n0, n1, n2, n3);
                *(float4*)(op + 4) = make_float4(n4, n5, n6, n7);
                op += R_DIM;

                ua = na; uc = nc;
            }
            barrier_lds_only();
        }
    } else {
        // ================= producers =================
        asm volatile("s_setprio 0" ::: "memory");
        const int pid = tid - 64;  // 0..447
        for (int k = 0; k < NPHASE; ++k) {
            if (k + 1 < NPHASE) {
                const int tb = NT * (k + 1) + 1;      // first t of next phase
                float* dst = &ubuf[(k + 1) & 1][0][0];
                for (int i = pid; i < NT * R_DIM; i += 448) {
                    const int tl = i >> 9;
                    const int r  = i & (R_DIM - 1);
                    const int t  = tb + tl;
                    if (t < T_DIM) {
                        const float4 xa = *(const float4*)(xb + t * D_DIM);
                        const float4 xc = *(const float4*)(xb + t * D_DIM + 4);
                        const float* wr = &Wl[r][0];
                        float u = xa.x * wr[0];
                        u = fmaf(xa.y, wr[1], u);
                        u = fmaf(xa.z, wr[2], u);
                        u = fmaf(xa.w, wr[3], u);
                        u = fmaf(xc.x, wr[4], u);
                        u = fmaf(xc.y, wr[5], u);
                        u = fmaf(xc.z, wr[6], u);
                        u = fmaf(xc.w, wr[7], u);
                        dst[i] = u;   // i == tl*512 + r
                    }
                }
            }
            barrier_lds_only();
        }
    }

    // Reference's final timestep is all zeros (d_out is poisoned 0xAA).
    out[(size_t)b * T_DIM * R_DIM + (size_t)(T_DIM - 1) * R_DIM + tid] = 0.0f;
}

extern "C" void kernel_launch(void* const* d_in, const int* in_sizes, int n_in,
                              void* d_out, int out_size, void* d_ws, size_t ws_size,
                              hipStream_t stream) {
    const float* x = (const float*)d_in[0];   // [B, T, D] fp32
    const float* W = (const float*)d_in[1];   // [R, D] fp32
    float* out = (float*)d_out;               // [B, T, R] fp32

    esn_kernel<<<dim3(B_DIM), dim3(512), 0, stream>>>(x, W, out);
}